// Round 9
// baseline (19.445 us; speedup 1.0000x reference)
//
#include <hip/hip_runtime.h>

#define BLK 256
#define DIM 32

typedef __attribute__((ext_vector_type(8))) short bf16x8;
typedef __attribute__((ext_vector_type(4))) float f32x4;

__device__ __forceinline__ unsigned short f2bf(float f) {
    unsigned u = __float_as_uint(f);
    unsigned r = ((u >> 16) & 1u) + 0x7fffu;   // round-to-nearest-even
    return (unsigned short)((u + r) >> 16);
}

// 4 threads per sample: lane = h*16 + lr, lr = sample-in-tile, h = quarter.
// Each thread's 32B u/q quarter gather IS its MFMA A-fragment chunk.
__global__ __launch_bounds__(BLK, 6) void mtn_fused(
    const int* __restrict__ uid, const int* __restrict__ iid,
    const float* __restrict__ Uw, const float* __restrict__ Qw,
    const float* __restrict__ Aw, const float* __restrict__ Bw,
    const float* __restrict__ W1, const float* __restrict__ b1g,
    const float* __restrict__ W2, const float* __restrict__ b2g,
    float* __restrict__ out, int batch)
{
    __shared__ __align__(16) unsigned short Bp[3 * 4 * 64 * 8];  // 12.3 KB, B-frag order

    const int t    = threadIdx.x;
    const int lane = t & 63;
    const int wave = t >> 6;
    const int lr   = lane & 15;    // sample within the wave's 16-row tile
    const int h    = lane >> 4;    // quarter of the embedding / MFMA k-group

    const int s = blockIdx.x * 64 + wave * 16 + lr;
    const bool valid = (s < batch);
    const int u_idx = valid ? uid[s] : 0;
    const int q_idx = valid ? iid[s] : 0;

    // quarter-row gathers (32 B each of u and q)
    const float4* up = (const float4*)(Uw + (long long)u_idx * DIM + h * 8);
    const float4* qp = (const float4*)(Qw + (long long)q_idx * DIM + h * 8);
    float4 uv0 = up[0], uv1 = up[1];
    float4 qv0 = qp[0], qv1 = qp[1];
    float av = 0.f;
    if (h == 0) av = Aw[u_idx] + Bw[q_idx];

    // ---- cooperative W1 -> Bp(bf16, B-fragment order) staging (as r8) ----
    // Bp[(((ks*4+n)*64)+l)*8+e] = bf16(W1[n*16+(l&15)][ks*32+((l>>4)<<3)+e])
    {
        const float4* w4 = (const float4*)W1;
#pragma unroll
        for (int it = 0; it < 6; ++it) {
            int base4 = t + it * BLK;            // 0..1535
            float4 w = w4[base4];
            int lin = base4 * 4;
            float we[4] = {w.x, w.y, w.z, w.w};
#pragma unroll
            for (int e4 = 0; e4 < 4; ++e4) {
                int lidx = lin + e4;
                int j = lidx / 96;
                int k = lidx - j * 96;
                int n  = j >> 4, jr = j & 15;
                int ks = k >> 5, kg = (k >> 3) & 3, e = k & 7;
                int l  = kg * 16 + jr;
                Bp[(((ks * 4 + n) << 6) + l) * 8 + e] = f2bf(we[e4]);
            }
        }
    }

    // ---- uq products, partial dot, A-fragments directly in registers ----
    bf16x8 a0, a1, a2;
    float dotp = 0.f;
    {
        const float ue[8] = {uv0.x,uv0.y,uv0.z,uv0.w, uv1.x,uv1.y,uv1.z,uv1.w};
        const float qe[8] = {qv0.x,qv0.y,qv0.z,qv0.w, qv1.x,qv1.y,qv1.z,qv1.w};
#pragma unroll
        for (int e = 0; e < 8; ++e) {
            float pp = ue[e] * qe[e];
            dotp += pp;
            a0[e] = (short)f2bf(ue[e]);
            a1[e] = (short)f2bf(qe[e]);
            a2[e] = (short)f2bf(pp);
        }
    }
    // quarters live in lanes h*16+lr -> reduce across h
    dotp += __shfl_xor(dotp, 16);
    dotp += __shfl_xor(dotp, 32);
    if (valid && h == 0) out[s] = dotp + av;

    __syncthreads();   // Bp ready

    // ---- per-lane layer-2 weights / biases (L2-hot broadcasts) ----
    float w2l[4], b1l[4];
#pragma unroll
    for (int n = 0; n < 4; ++n) {
        w2l[n] = W2[n * 16 + lr];
        b1l[n] = b1g[n * 16 + lr];
    }
    const float b2v = b2g[0];

    f32x4 c0 = {b1l[0], b1l[0], b1l[0], b1l[0]};
    f32x4 c1 = {b1l[1], b1l[1], b1l[1], b1l[1]};
    f32x4 c2 = {b1l[2], b1l[2], b1l[2], b1l[2]};
    f32x4 c3 = {b1l[3], b1l[3], b1l[3], b1l[3]};

    // ks-split B loads keep only 16 bfrag VGPRs live at a time
    const bf16x8* bp = (const bf16x8*)Bp;
    {
        bf16x8 b0 = bp[0 * 64 + lane], b1 = bp[1 * 64 + lane];
        bf16x8 b2 = bp[2 * 64 + lane], b3 = bp[3 * 64 + lane];
        c0 = __builtin_amdgcn_mfma_f32_16x16x32_bf16(a0, b0, c0, 0, 0, 0);
        c1 = __builtin_amdgcn_mfma_f32_16x16x32_bf16(a0, b1, c1, 0, 0, 0);
        c2 = __builtin_amdgcn_mfma_f32_16x16x32_bf16(a0, b2, c2, 0, 0, 0);
        c3 = __builtin_amdgcn_mfma_f32_16x16x32_bf16(a0, b3, c3, 0, 0, 0);
    }
    {
        bf16x8 b0 = bp[4 * 64 + lane], b1 = bp[5 * 64 + lane];
        bf16x8 b2 = bp[6 * 64 + lane], b3 = bp[7 * 64 + lane];
        c0 = __builtin_amdgcn_mfma_f32_16x16x32_bf16(a1, b0, c0, 0, 0, 0);
        c1 = __builtin_amdgcn_mfma_f32_16x16x32_bf16(a1, b1, c1, 0, 0, 0);
        c2 = __builtin_amdgcn_mfma_f32_16x16x32_bf16(a1, b2, c2, 0, 0, 0);
        c3 = __builtin_amdgcn_mfma_f32_16x16x32_bf16(a1, b3, c3, 0, 0, 0);
    }
    {
        bf16x8 b0 = bp[8 * 64 + lane], b1 = bp[9 * 64 + lane];
        bf16x8 b2 = bp[10 * 64 + lane], b3 = bp[11 * 64 + lane];
        c0 = __builtin_amdgcn_mfma_f32_16x16x32_bf16(a2, b0, c0, 0, 0, 0);
        c1 = __builtin_amdgcn_mfma_f32_16x16x32_bf16(a2, b1, c1, 0, 0, 0);
        c2 = __builtin_amdgcn_mfma_f32_16x16x32_bf16(a2, b2, c2, 0, 0, 0);
        c3 = __builtin_amdgcn_mfma_f32_16x16x32_bf16(a2, b3, c3, 0, 0, 0);
    }

    // layer 2: score = relu( sum_j relu(h_j)*W2[j] + b2 )
    float tot[4];
#pragma unroll
    for (int r = 0; r < 4; ++r) {
        float p = fmaxf(c0[r], 0.f) * w2l[0] + fmaxf(c1[r], 0.f) * w2l[1]
                + fmaxf(c2[r], 0.f) * w2l[2] + fmaxf(c3[r], 0.f) * w2l[3];
        p += __shfl_xor(p, 1);
        p += __shfl_xor(p, 2);
        p += __shfl_xor(p, 4);
        p += __shfl_xor(p, 8);
        tot[r] = p;
    }
    if (lr < 4) {
        int so = blockIdx.x * 64 + wave * 16 + h * 4 + lr;
        if (so < batch) out[batch + so] = fmaxf(tot[lr] + b2v, 0.f);
    }
}

extern "C" void kernel_launch(void* const* d_in, const int* in_sizes, int n_in,
                              void* d_out, int out_size, void* d_ws, size_t ws_size,
                              hipStream_t stream) {
    const int*   uid = (const int*)  d_in[0];
    const int*   iid = (const int*)  d_in[1];
    const float* Uw  = (const float*)d_in[2];
    const float* Qw  = (const float*)d_in[3];
    const float* Aw  = (const float*)d_in[4];
    const float* Bw  = (const float*)d_in[5];
    const float* W1  = (const float*)d_in[6];
    const float* b1  = (const float*)d_in[7];
    const float* W2  = (const float*)d_in[8];
    const float* b2  = (const float*)d_in[9];
    float* out = (float*)d_out;
    int batch = in_sizes[0];

    int blocks = (batch + 63) / 64;
    hipLaunchKernelGGL(mtn_fused, dim3(blocks), dim3(BLK), 0, stream,
                       uid, iid, Uw, Qw, Aw, Bw, W1, b1, W2, b2, out, batch);
}

// Round 10
// 18.613 us; speedup vs baseline: 1.0447x; 1.0447x over previous
//
#include <hip/hip_runtime.h>

#define BLK 256
#define DIM 32

typedef __attribute__((ext_vector_type(8))) short bf16x8;
typedef __attribute__((ext_vector_type(4))) float f32x4;

__device__ __forceinline__ unsigned short f2bf(float f) {
    unsigned u = __float_as_uint(f);
    unsigned r = ((u >> 16) & 1u) + 0x7fffu;   // round-to-nearest-even
    return (unsigned short)((u + r) >> 16);
}

// 4 threads per sample, 2 samples per thread.
// lane = h*16 + lr : lr = sample-in-tile, h = quarter / MFMA k-group.
// Wave covers samples [base, base+32): tile0 = base+lr, tile1 = base+16+lr.
__global__ __launch_bounds__(BLK, 4) void mtn_fused(
    const int* __restrict__ uid, const int* __restrict__ iid,
    const float* __restrict__ Uw, const float* __restrict__ Qw,
    const float* __restrict__ Aw, const float* __restrict__ Bw,
    const float* __restrict__ W1, const float* __restrict__ b1g,
    const float* __restrict__ W2, const float* __restrict__ b2g,
    float* __restrict__ out, int batch)
{
    __shared__ __align__(16) unsigned short Bp[3 * 4 * 64 * 8];  // 12.3 KB, B-frag order

    const int t    = threadIdx.x;
    const int lane = t & 63;
    const int wave = t >> 6;
    const int lr   = lane & 15;
    const int h    = lane >> 4;

    const int base = blockIdx.x * 128 + wave * 32;
    const int s0 = base + lr;
    const int s1 = base + 16 + lr;
    const bool v0 = (s0 < batch), v1 = (s1 < batch);
    const int u0 = v0 ? uid[s0] : 0, q0i = v0 ? iid[s0] : 0;
    const int u1 = v1 ? uid[s1] : 0, q1i = v1 ? iid[s1] : 0;

    // 16 quarter-row float4 gathers issued back-to-back (max in-flight)
    const float4* up0 = (const float4*)(Uw + (long long)u0  * DIM + h * 8);
    const float4* qp0 = (const float4*)(Qw + (long long)q0i * DIM + h * 8);
    const float4* up1 = (const float4*)(Uw + (long long)u1  * DIM + h * 8);
    const float4* qp1 = (const float4*)(Qw + (long long)q1i * DIM + h * 8);
    float4 ua0 = up0[0], ua1 = up0[1];
    float4 qa0 = qp0[0], qa1 = qp0[1];
    float4 ub0 = up1[0], ub1 = up1[1];
    float4 qb0 = qp1[0], qb1 = qp1[1];
    float av0 = 0.f, av1 = 0.f;
    if (h == 0) {
        av0 = Aw[u0] + Bw[q0i];
        av1 = Aw[u1] + Bw[q1i];
    }

    // ---- cooperative W1 -> Bp(bf16, B-fragment order), once per 128 samples ----
    // Bp[(((ks*4+n)*64)+l)*8+e] = bf16(W1[n*16+(l&15)][ks*32+((l>>4)<<3)+e])
    {
        const float4* w4 = (const float4*)W1;
#pragma unroll
        for (int it = 0; it < 6; ++it) {
            int base4 = t + it * BLK;            // 0..1535
            float4 w = w4[base4];
            int lin = base4 * 4;
            float we[4] = {w.x, w.y, w.z, w.w};
#pragma unroll
            for (int e4 = 0; e4 < 4; ++e4) {
                int lidx = lin + e4;
                int j = lidx / 96;
                int k = lidx - j * 96;
                int n  = j >> 4, jr = j & 15;
                int ks = k >> 5, kg = (k >> 3) & 3, e = k & 7;
                int l  = kg * 16 + jr;
                Bp[(((ks * 4 + n) << 6) + l) * 8 + e] = f2bf(we[e4]);
            }
        }
    }

    // ---- A-fragments + partial dots, straight from registers ----
    bf16x8 x0a, x0b, x0c, x1a, x1b, x1c;
    float d0 = 0.f, d1 = 0.f;
    {
        const float ue0[8] = {ua0.x,ua0.y,ua0.z,ua0.w, ua1.x,ua1.y,ua1.z,ua1.w};
        const float qe0[8] = {qa0.x,qa0.y,qa0.z,qa0.w, qa1.x,qa1.y,qa1.z,qa1.w};
        const float ue1[8] = {ub0.x,ub0.y,ub0.z,ub0.w, ub1.x,ub1.y,ub1.z,ub1.w};
        const float qe1[8] = {qb0.x,qb0.y,qb0.z,qb0.w, qb1.x,qb1.y,qb1.z,qb1.w};
#pragma unroll
        for (int e = 0; e < 8; ++e) {
            float p0 = ue0[e] * qe0[e];
            float p1 = ue1[e] * qe1[e];
            d0 += p0;  d1 += p1;
            x0a[e] = (short)f2bf(ue0[e]);
            x0b[e] = (short)f2bf(qe0[e]);
            x0c[e] = (short)f2bf(p0);
            x1a[e] = (short)f2bf(ue1[e]);
            x1b[e] = (short)f2bf(qe1[e]);
            x1c[e] = (short)f2bf(p1);
        }
    }
    d0 += __shfl_xor(d0, 16);  d0 += __shfl_xor(d0, 32);
    d1 += __shfl_xor(d1, 16);  d1 += __shfl_xor(d1, 32);
    if (v0 && h == 0) out[s0] = d0 + av0;
    if (v1 && h == 0) out[s1] = d1 + av1;

    __syncthreads();   // Bp ready

    float w2l[4], b1l[4];
#pragma unroll
    for (int n = 0; n < 4; ++n) {
        w2l[n] = W2[n * 16 + lr];
        b1l[n] = b1g[n * 16 + lr];
    }
    const float b2v = b2g[0];

    f32x4 c00 = {b1l[0],b1l[0],b1l[0],b1l[0]}, c01 = {b1l[1],b1l[1],b1l[1],b1l[1]};
    f32x4 c02 = {b1l[2],b1l[2],b1l[2],b1l[2]}, c03 = {b1l[3],b1l[3],b1l[3],b1l[3]};
    f32x4 c10 = c00, c11 = c01, c12 = c02, c13 = c03;

    // each B-fragment loaded once, used by both sample-tiles
    const bf16x8* bp = (const bf16x8*)Bp;
    {
        bf16x8 b0 = bp[0*64+lane], b1 = bp[1*64+lane], b2 = bp[2*64+lane], b3 = bp[3*64+lane];
        c00 = __builtin_amdgcn_mfma_f32_16x16x32_bf16(x0a, b0, c00, 0, 0, 0);
        c10 = __builtin_amdgcn_mfma_f32_16x16x32_bf16(x1a, b0, c10, 0, 0, 0);
        c01 = __builtin_amdgcn_mfma_f32_16x16x32_bf16(x0a, b1, c01, 0, 0, 0);
        c11 = __builtin_amdgcn_mfma_f32_16x16x32_bf16(x1a, b1, c11, 0, 0, 0);
        c02 = __builtin_amdgcn_mfma_f32_16x16x32_bf16(x0a, b2, c02, 0, 0, 0);
        c12 = __builtin_amdgcn_mfma_f32_16x16x32_bf16(x1a, b2, c12, 0, 0, 0);
        c03 = __builtin_amdgcn_mfma_f32_16x16x32_bf16(x0a, b3, c03, 0, 0, 0);
        c13 = __builtin_amdgcn_mfma_f32_16x16x32_bf16(x1a, b3, c13, 0, 0, 0);
    }
    {
        bf16x8 b0 = bp[4*64+lane], b1 = bp[5*64+lane], b2 = bp[6*64+lane], b3 = bp[7*64+lane];
        c00 = __builtin_amdgcn_mfma_f32_16x16x32_bf16(x0b, b0, c00, 0, 0, 0);
        c10 = __builtin_amdgcn_mfma_f32_16x16x32_bf16(x1b, b0, c10, 0, 0, 0);
        c01 = __builtin_amdgcn_mfma_f32_16x16x32_bf16(x0b, b1, c01, 0, 0, 0);
        c11 = __builtin_amdgcn_mfma_f32_16x16x32_bf16(x1b, b1, c11, 0, 0, 0);
        c02 = __builtin_amdgcn_mfma_f32_16x16x32_bf16(x0b, b2, c02, 0, 0, 0);
        c12 = __builtin_amdgcn_mfma_f32_16x16x32_bf16(x1b, b2, c12, 0, 0, 0);
        c03 = __builtin_amdgcn_mfma_f32_16x16x32_bf16(x0b, b3, c03, 0, 0, 0);
        c13 = __builtin_amdgcn_mfma_f32_16x16x32_bf16(x1b, b3, c13, 0, 0, 0);
    }
    {
        bf16x8 b0 = bp[8*64+lane], b1 = bp[9*64+lane], b2 = bp[10*64+lane], b3 = bp[11*64+lane];
        c00 = __builtin_amdgcn_mfma_f32_16x16x32_bf16(x0c, b0, c00, 0, 0, 0);
        c10 = __builtin_amdgcn_mfma_f32_16x16x32_bf16(x1c, b0, c10, 0, 0, 0);
        c01 = __builtin_amdgcn_mfma_f32_16x16x32_bf16(x0c, b1, c01, 0, 0, 0);
        c11 = __builtin_amdgcn_mfma_f32_16x16x32_bf16(x1c, b1, c11, 0, 0, 0);
        c02 = __builtin_amdgcn_mfma_f32_16x16x32_bf16(x0c, b2, c02, 0, 0, 0);
        c12 = __builtin_amdgcn_mfma_f32_16x16x32_bf16(x1c, b2, c12, 0, 0, 0);
        c03 = __builtin_amdgcn_mfma_f32_16x16x32_bf16(x0c, b3, c03, 0, 0, 0);
        c13 = __builtin_amdgcn_mfma_f32_16x16x32_bf16(x1c, b3, c13, 0, 0, 0);
    }

    // ---- layer 2 + writes, per tile ----
#pragma unroll
    for (int tile = 0; tile < 2; ++tile) {
        f32x4 e0 = tile ? c10 : c00, e1 = tile ? c11 : c01;
        f32x4 e2 = tile ? c12 : c02, e3 = tile ? c13 : c03;
        float tot[4];
#pragma unroll
        for (int r = 0; r < 4; ++r) {
            float p = fmaxf(e0[r], 0.f) * w2l[0] + fmaxf(e1[r], 0.f) * w2l[1]
                    + fmaxf(e2[r], 0.f) * w2l[2] + fmaxf(e3[r], 0.f) * w2l[3];
            p += __shfl_xor(p, 1);
            p += __shfl_xor(p, 2);
            p += __shfl_xor(p, 4);
            p += __shfl_xor(p, 8);
            tot[r] = p;
        }
        if (lr < 4) {
            int so = base + tile * 16 + h * 4 + lr;
            if (so < batch) out[batch + so] = fmaxf(tot[lr] + b2v, 0.f);
        }
    }
}

extern "C" void kernel_launch(void* const* d_in, const int* in_sizes, int n_in,
                              void* d_out, int out_size, void* d_ws, size_t ws_size,
                              hipStream_t stream) {
    const int*   uid = (const int*)  d_in[0];
    const int*   iid = (const int*)  d_in[1];
    const float* Uw  = (const float*)d_in[2];
    const float* Qw  = (const float*)d_in[3];
    const float* Aw  = (const float*)d_in[4];
    const float* Bw  = (const float*)d_in[5];
    const float* W1  = (const float*)d_in[6];
    const float* b1  = (const float*)d_in[7];
    const float* W2  = (const float*)d_in[8];
    const float* b2  = (const float*)d_in[9];
    float* out = (float*)d_out;
    int batch = in_sizes[0];

    int blocks = (batch + 127) / 128;
    hipLaunchKernelGGL(mtn_fused, dim3(blocks), dim3(BLK), 0, stream,
                       uid, iid, Uw, Qw, Aw, Bw, W1, b1, W2, b2, out, batch);
}